// Round 2
// baseline (267.200 us; speedup 1.0000x reference)
//
#include <hip/hip_runtime.h>
#include <cstdint>

// Shapes fixed by the harness:
// u, delta, z: (b=2, d=1024, l=2048) fp32; A: (d, n=16); B, C: (b, n, l); D: (d,)
constexpr int kD = 1024;
constexpr int kN = 16;
constexpr int kL = 2048;
constexpr int BLOCK = 256;
constexpr int T  = kL / BLOCK;   // 8 timesteps per thread
constexpr int NW = BLOCK / 64;   // 4 waves per block
constexpr int NH = 8;            // states per half (kN/2) -> halves live registers
constexpr float LOG2E = 1.44269504088896340736f;

__device__ __forceinline__ float fast_exp2(float x) { return __builtin_amdgcn_exp2f(x); }
__device__ __forceinline__ float fast_exp(float x)  { return __builtin_amdgcn_exp2f(x * LOG2E); }
__device__ __forceinline__ float softplus_f(float x) {
  return (x > 20.0f) ? x : __logf(1.0f + fast_exp(x));
}

__global__ __launch_bounds__(BLOCK, 5)   // cap VGPRs at ~102 -> 5 waves/SIMD
void selscan_kernel(const float* __restrict__ u,  const float* __restrict__ dl,
                    const float* __restrict__ A,  const float* __restrict__ Bm,
                    const float* __restrict__ Cm, const float* __restrict__ Dv,
                    const float* __restrict__ zm, float* __restrict__ out)
{
  const int row  = blockIdx.x;          // b*kD + d
  const int b    = row >> 10;           // kD = 1024
  const int d    = row & (kD - 1);
  const int tid  = threadIdx.x;
  const int lane = tid & 63;
  const int wid  = tid >> 6;

  const size_t roff = (size_t)row * kL;
  const float4* u4 = reinterpret_cast<const float4*>(u  + roff);
  const float4* d4 = reinterpret_cast<const float4*>(dl + roff);

  // Per-thread chunk [tid*T, tid*T+T): softplus(delta), delta*u kept in regs.
  // u itself is refetched in the epilogue (frees 8 VGPRs; HBM has 20x headroom).
  float sp[T], du[T];
  {
    float4 a0 = u4[tid*2+0], a1 = u4[tid*2+1];
    float uu[T] = {a0.x,a0.y,a0.z,a0.w,a1.x,a1.y,a1.z,a1.w};
    float4 b0 = d4[tid*2+0], b1 = d4[tid*2+1];
    float dv[T] = {b0.x,b0.y,b0.z,b0.w,b1.x,b1.y,b1.z,b1.w};
    #pragma unroll
    for (int i = 0; i < T; ++i) { sp[i] = softplus_f(dv[i]); du[i] = sp[i] * uu[i]; }
  }

  float y[T];
  #pragma unroll
  for (int i = 0; i < T; ++i) y[i] = 0.0f;

  __shared__ float sA[NW][NH], sX[NW][NH], eX[NW][NH];

  #pragma unroll 1                      // keep halves sequential: live-range control
  for (int half = 0; half < 2; ++half) {
    // A sub-row, pre-scaled by log2(e): inner loop is a single v_exp_f32
    float Ar[NH];
    {
      const float4* A4 = reinterpret_cast<const float4*>(A + (size_t)d * kN + half * NH);
      float4 v0 = A4[0], v1 = A4[1];
      Ar[0]=v0.x*LOG2E; Ar[1]=v0.y*LOG2E; Ar[2]=v0.z*LOG2E; Ar[3]=v0.w*LOG2E;
      Ar[4]=v1.x*LOG2E; Ar[5]=v1.y*LOG2E; Ar[6]=v1.z*LOG2E; Ar[7]=v1.w*LOG2E;
    }
    const float4* B4 = reinterpret_cast<const float4*>(Bm + ((size_t)b * kN + half * NH) * kL);
    const float4* C4 = reinterpret_cast<const float4*>(Cm + ((size_t)b * kN + half * NH) * kL);

    // ---- Pass A: local scan from zero -> chunk aggregates (prod a, h_end)
    float cA[NH], cX[NH];
    #pragma unroll
    for (int n = 0; n < NH; ++n) {
      float4 b0 = B4[n*(kL/4) + tid*2 + 0];
      float4 b1 = B4[n*(kL/4) + tid*2 + 1];
      float Bv[T] = {b0.x,b0.y,b0.z,b0.w,b1.x,b1.y,b1.z,b1.w};
      float ap = 1.0f, h = 0.0f;
      #pragma unroll
      for (int i = 0; i < T; ++i) {
        float a = fast_exp2(sp[i] * Ar[n]);
        h  = a * h + du[i] * Bv[i];
        ap *= a;
      }
      cA[n] = ap; cX[n] = h;
    }

    // ---- Wave-level inclusive scan (Hillis-Steele, branchless identity select)
    #pragma unroll
    for (int n = 0; n < NH; ++n) {
      float a = cA[n], x = cX[n];
      #pragma unroll
      for (int off = 1; off < 64; off <<= 1) {
        float au = __shfl_up(a, (unsigned)off, 64);
        float xu = __shfl_up(x, (unsigned)off, 64);
        bool m = (lane >= off);
        au = m ? au : 1.0f;
        xu = m ? xu : 0.0f;
        x = a * xu + x;
        a = a * au;
      }
      cA[n] = a; cX[n] = x;
    }

    // ---- Cross-wave scan (4 waves) through LDS
    if (lane == 63) {
      #pragma unroll
      for (int n = 0; n < NH; ++n) { sA[wid][n] = cA[n]; sX[wid][n] = cX[n]; }
    }
    __syncthreads();
    if (tid < NH) {
      const int n = tid;
      float a = 1.0f, x = 0.0f;
      #pragma unroll
      for (int w = 0; w < NW; ++w) {
        eX[w][n] = x;                    // exclusive x-prefix for wave w
        x = sA[w][n] * x + sX[w][n];
        a = a * sA[w][n];
        (void)a;
      }
    }
    __syncthreads();

    // ---- Per-thread initial state h_{start-1}[n], then Pass B fused with y
    #pragma unroll
    for (int n = 0; n < NH; ++n) {
      float al = __shfl_up(cA[n], 1u, 64);
      float xl = __shfl_up(cX[n], 1u, 64);
      if (lane == 0) { al = 1.0f; xl = 0.0f; }
      float h0 = al * eX[wid][n] + xl;

      float4 b0 = B4[n*(kL/4) + tid*2 + 0];
      float4 b1 = B4[n*(kL/4) + tid*2 + 1];
      float4 c0 = C4[n*(kL/4) + tid*2 + 0];
      float4 c1 = C4[n*(kL/4) + tid*2 + 1];
      float Bv[T] = {b0.x,b0.y,b0.z,b0.w,b1.x,b1.y,b1.z,b1.w};
      float Cv[T] = {c0.x,c0.y,c0.z,c0.w,c1.x,c1.y,c1.z,c1.w};
      float h = h0;
      #pragma unroll
      for (int i = 0; i < T; ++i) {
        float a = fast_exp2(sp[i] * Ar[n]);
        h = a * h + du[i] * Bv[i];
        y[i] += Cv[i] * h;
      }
    }
    __syncthreads();   // protect sA/sX/eX reuse across halves
  }

  // ---- Epilogue: + u*D, * silu(z), store  (u refetched here)
  const float Dd = Dv[d];
  const float4* z4 = reinterpret_cast<const float4*>(zm + roff);
  float4 z0 = z4[tid*2+0], z1 = z4[tid*2+1];
  float zv[T] = {z0.x,z0.y,z0.z,z0.w,z1.x,z1.y,z1.z,z1.w};
  float4 a0 = u4[tid*2+0], a1 = u4[tid*2+1];
  float uu[T] = {a0.x,a0.y,a0.z,a0.w,a1.x,a1.y,a1.z,a1.w};
  float ov[T];
  #pragma unroll
  for (int i = 0; i < T; ++i) {
    float yy  = y[i] + uu[i] * Dd;
    float sig = 1.0f / (1.0f + fast_exp(-zv[i]));
    ov[i] = yy * zv[i] * sig;
  }
  float4* out4 = reinterpret_cast<float4*>(out + roff);
  out4[tid*2+0] = make_float4(ov[0], ov[1], ov[2], ov[3]);
  out4[tid*2+1] = make_float4(ov[4], ov[5], ov[6], ov[7]);
}

extern "C" void kernel_launch(void* const* d_in, const int* in_sizes, int n_in,
                              void* d_out, int out_size, void* d_ws, size_t ws_size,
                              hipStream_t stream)
{
  const float* u  = (const float*)d_in[0];
  const float* dl = (const float*)d_in[1];
  const float* A  = (const float*)d_in[2];
  const float* Bm = (const float*)d_in[3];
  const float* Cm = (const float*)d_in[4];
  const float* Dv = (const float*)d_in[5];
  const float* zm = (const float*)d_in[6];
  float* out = (float*)d_out;
  const int rows = in_sizes[0] / kL;   // b*d = 2048
  selscan_kernel<<<rows, BLOCK, 0, stream>>>(u, dl, A, Bm, Cm, Dv, zm, out);
}

// Round 3
// 204.963 us; speedup vs baseline: 1.3037x; 1.3037x over previous
//
#include <hip/hip_runtime.h>
#include <cstdint>

// Shapes fixed by the harness:
// u, delta, z: (b=2, d=1024, l=2048) fp32; A: (d, n=16); B, C: (b, n, l); D: (d,)
constexpr int kD = 1024;
constexpr int kN = 16;
constexpr int kL = 2048;
constexpr int BLOCK = 256;
constexpr int T  = kL / BLOCK;   // 8 timesteps per thread
constexpr int NW = BLOCK / 64;   // 4 waves per block
constexpr int NH = 8;            // states per half (kN/2) -> halves live registers
constexpr float LOG2E = 1.44269504088896340736f;

__device__ __forceinline__ float fast_exp2(float x) { return __builtin_amdgcn_exp2f(x); }
__device__ __forceinline__ float fast_exp(float x)  { return __builtin_amdgcn_exp2f(x * LOG2E); }
__device__ __forceinline__ float softplus_f(float x) {
  return (x > 20.0f) ? x : __logf(1.0f + fast_exp(x));
}

// 4 waves/SIMD -> 128-VGPR budget. R2's (256,5)=102-reg budget made the
// allocator spill-cascade down to 48 VGPRs with ~600 MB/dispatch of scratch
// traffic; the half-split kernel needs ~110 regs, so 128 should be spill-free.
__global__ __launch_bounds__(BLOCK, 4)
void selscan_kernel(const float* __restrict__ u,  const float* __restrict__ dl,
                    const float* __restrict__ A,  const float* __restrict__ Bm,
                    const float* __restrict__ Cm, const float* __restrict__ Dv,
                    const float* __restrict__ zm, float* __restrict__ out)
{
  const int row  = blockIdx.x;          // b*kD + d
  const int b    = row >> 10;           // kD = 1024
  const int d    = row & (kD - 1);
  const int tid  = threadIdx.x;
  const int lane = tid & 63;
  const int wid  = tid >> 6;

  const size_t roff = (size_t)row * kL;
  const float4* u4 = reinterpret_cast<const float4*>(u  + roff);
  const float4* d4 = reinterpret_cast<const float4*>(dl + roff);

  // Per-thread chunk [tid*T, tid*T+T): softplus(delta), delta*u kept in regs.
  // u itself is refetched in the epilogue (frees 8 VGPRs; it is L3-resident).
  float sp[T], du[T];
  {
    float4 a0 = u4[tid*2+0], a1 = u4[tid*2+1];
    float uu[T] = {a0.x,a0.y,a0.z,a0.w,a1.x,a1.y,a1.z,a1.w};
    float4 b0 = d4[tid*2+0], b1 = d4[tid*2+1];
    float dv[T] = {b0.x,b0.y,b0.z,b0.w,b1.x,b1.y,b1.z,b1.w};
    #pragma unroll
    for (int i = 0; i < T; ++i) { sp[i] = softplus_f(dv[i]); du[i] = sp[i] * uu[i]; }
  }

  float y[T];
  #pragma unroll
  for (int i = 0; i < T; ++i) y[i] = 0.0f;

  __shared__ float sA[NW][NH], sX[NW][NH], eX[NW][NH];

  #pragma unroll 1                      // keep halves sequential: live-range control
  for (int half = 0; half < 2; ++half) {
    // A sub-row, pre-scaled by log2(e): inner loop is a single v_exp_f32
    float Ar[NH];
    {
      const float4* A4 = reinterpret_cast<const float4*>(A + (size_t)d * kN + half * NH);
      float4 v0 = A4[0], v1 = A4[1];
      Ar[0]=v0.x*LOG2E; Ar[1]=v0.y*LOG2E; Ar[2]=v0.z*LOG2E; Ar[3]=v0.w*LOG2E;
      Ar[4]=v1.x*LOG2E; Ar[5]=v1.y*LOG2E; Ar[6]=v1.z*LOG2E; Ar[7]=v1.w*LOG2E;
    }
    const float4* B4 = reinterpret_cast<const float4*>(Bm + ((size_t)b * kN + half * NH) * kL);
    const float4* C4 = reinterpret_cast<const float4*>(Cm + ((size_t)b * kN + half * NH) * kL);

    // ---- Pass A: local scan from zero -> chunk aggregates (prod a, h_end)
    float cA[NH], cX[NH];
    #pragma unroll
    for (int n = 0; n < NH; ++n) {
      float4 b0 = B4[n*(kL/4) + tid*2 + 0];
      float4 b1 = B4[n*(kL/4) + tid*2 + 1];
      float Bv[T] = {b0.x,b0.y,b0.z,b0.w,b1.x,b1.y,b1.z,b1.w};
      float ap = 1.0f, h = 0.0f;
      #pragma unroll
      for (int i = 0; i < T; ++i) {
        float a = fast_exp2(sp[i] * Ar[n]);
        h  = a * h + du[i] * Bv[i];
        ap *= a;
      }
      cA[n] = ap; cX[n] = h;
    }

    // ---- Wave-level inclusive scan (Hillis-Steele, branchless identity select)
    #pragma unroll
    for (int n = 0; n < NH; ++n) {
      float a = cA[n], x = cX[n];
      #pragma unroll
      for (int off = 1; off < 64; off <<= 1) {
        float au = __shfl_up(a, (unsigned)off, 64);
        float xu = __shfl_up(x, (unsigned)off, 64);
        bool m = (lane >= off);
        au = m ? au : 1.0f;
        xu = m ? xu : 0.0f;
        x = a * xu + x;
        a = a * au;
      }
      cA[n] = a; cX[n] = x;
    }

    // ---- Cross-wave scan (4 waves) through LDS
    if (lane == 63) {
      #pragma unroll
      for (int n = 0; n < NH; ++n) { sA[wid][n] = cA[n]; sX[wid][n] = cX[n]; }
    }
    __syncthreads();
    if (tid < NH) {
      const int n = tid;
      float x = 0.0f;
      #pragma unroll
      for (int w = 0; w < NW; ++w) {
        eX[w][n] = x;                    // exclusive x-prefix for wave w
        x = sA[w][n] * x + sX[w][n];
      }
    }
    __syncthreads();

    // ---- Per-thread initial state h_{start-1}[n], then Pass B fused with y
    #pragma unroll
    for (int n = 0; n < NH; ++n) {
      float al = __shfl_up(cA[n], 1u, 64);
      float xl = __shfl_up(cX[n], 1u, 64);
      if (lane == 0) { al = 1.0f; xl = 0.0f; }
      float h0 = al * eX[wid][n] + xl;

      float4 b0 = B4[n*(kL/4) + tid*2 + 0];
      float4 b1 = B4[n*(kL/4) + tid*2 + 1];
      float4 c0 = C4[n*(kL/4) + tid*2 + 0];
      float4 c1 = C4[n*(kL/4) + tid*2 + 1];
      float Bv[T] = {b0.x,b0.y,b0.z,b0.w,b1.x,b1.y,b1.z,b1.w};
      float Cv[T] = {c0.x,c0.y,c0.z,c0.w,c1.x,c1.y,c1.z,c1.w};
      float h = h0;
      #pragma unroll
      for (int i = 0; i < T; ++i) {
        float a = fast_exp2(sp[i] * Ar[n]);
        h = a * h + du[i] * Bv[i];
        y[i] += Cv[i] * h;
      }
    }
    __syncthreads();   // protect sA/sX/eX reuse across halves
  }

  // ---- Epilogue: + u*D, * silu(z), store  (u refetched here)
  const float Dd = Dv[d];
  const float4* z4 = reinterpret_cast<const float4*>(zm + roff);
  float4 z0 = z4[tid*2+0], z1 = z4[tid*2+1];
  float zv[T] = {z0.x,z0.y,z0.z,z0.w,z1.x,z1.y,z1.z,z1.w};
  float4 a0 = u4[tid*2+0], a1 = u4[tid*2+1];
  float uu[T] = {a0.x,a0.y,a0.z,a0.w,a1.x,a1.y,a1.z,a1.w};
  float ov[T];
  #pragma unroll
  for (int i = 0; i < T; ++i) {
    float yy  = y[i] + uu[i] * Dd;
    float sig = 1.0f / (1.0f + fast_exp(-zv[i]));
    ov[i] = yy * zv[i] * sig;
  }
  float4* out4 = reinterpret_cast<float4*>(out + roff);
  out4[tid*2+0] = make_float4(ov[0], ov[1], ov[2], ov[3]);
  out4[tid*2+1] = make_float4(ov[4], ov[5], ov[6], ov[7]);
}

extern "C" void kernel_launch(void* const* d_in, const int* in_sizes, int n_in,
                              void* d_out, int out_size, void* d_ws, size_t ws_size,
                              hipStream_t stream)
{
  const float* u  = (const float*)d_in[0];
  const float* dl = (const float*)d_in[1];
  const float* A  = (const float*)d_in[2];
  const float* Bm = (const float*)d_in[3];
  const float* Cm = (const float*)d_in[4];
  const float* Dv = (const float*)d_in[5];
  const float* zm = (const float*)d_in[6];
  float* out = (float*)d_out;
  const int rows = in_sizes[0] / kL;   // b*d = 2048
  selscan_kernel<<<rows, BLOCK, 0, stream>>>(u, dl, A, Bm, Cm, Dv, zm, out);
}

// Round 4
// 171.904 us; speedup vs baseline: 1.5544x; 1.1923x over previous
//
#include <hip/hip_runtime.h>
#include <cstdint>

// Shapes fixed by the harness:
// u, delta, z: (b=2, d=1024, l=2048) fp32; A: (d, n=16); B, C: (b, n, l); D: (d,)
constexpr int kD = 1024;
constexpr int kN = 16;
constexpr int kL = 2048;
constexpr int BLOCK = 512;       // R4: bigger block, shorter per-thread chunk
constexpr int T  = kL / BLOCK;   // 4 timesteps per thread (one float4)
constexpr int NW = BLOCK / 64;   // 8 waves per block
constexpr int NH = 8;            // states per half (kN/2) keeps live arrays small
constexpr float LOG2E = 1.44269504088896340736f;

__device__ __forceinline__ float fast_exp2(float x) { return __builtin_amdgcn_exp2f(x); }
__device__ __forceinline__ float fast_exp(float x)  { return __builtin_amdgcn_exp2f(x * LOG2E); }
__device__ __forceinline__ float softplus_f(float x) {
  return (x > 20.0f) ? x : __logf(1.0f + fast_exp(x));
}

// NOTE: single-arg launch_bounds only. Any min-waves hint (R2: (256,5) -> 48
// VGPR, R3: (256,4) -> 64 VGPR) makes the allocator spill-cascade with
// 150-350 MB/dispatch of scratch traffic. Structural pressure reduction
// (T=4) is how we get occupancy instead.
__global__ __launch_bounds__(BLOCK)
void selscan_kernel(const float* __restrict__ u,  const float* __restrict__ dl,
                    const float* __restrict__ A,  const float* __restrict__ Bm,
                    const float* __restrict__ Cm, const float* __restrict__ Dv,
                    const float* __restrict__ zm, float* __restrict__ out)
{
  const int row  = blockIdx.x;          // b*kD + d
  const int b    = row >> 10;           // kD = 1024
  const int d    = row & (kD - 1);
  const int tid  = threadIdx.x;
  const int lane = tid & 63;
  const int wid  = tid >> 6;

  const size_t roff = (size_t)row * kL;
  const float4* u4 = reinterpret_cast<const float4*>(u  + roff);
  const float4* d4 = reinterpret_cast<const float4*>(dl + roff);

  // Per-thread chunk [tid*T, tid*T+T): softplus(delta), delta*u in regs.
  // u refetched in the epilogue (L2-resident by then).
  float sp[T], du[T];
  {
    float4 a0 = u4[tid];
    float uu[T] = {a0.x, a0.y, a0.z, a0.w};
    float4 b0 = d4[tid];
    float dv[T] = {b0.x, b0.y, b0.z, b0.w};
    #pragma unroll
    for (int i = 0; i < T; ++i) { sp[i] = softplus_f(dv[i]); du[i] = sp[i] * uu[i]; }
  }

  float y[T];
  #pragma unroll
  for (int i = 0; i < T; ++i) y[i] = 0.0f;

  __shared__ float sA[NW][NH], sX[NW][NH], eX[NW][NH];

  #pragma unroll 1                      // halves sequential: live-range control
  for (int half = 0; half < 2; ++half) {
    // A sub-row, pre-scaled by log2(e): inner loop is a single v_exp_f32
    float Ar[NH];
    {
      const float4* A4 = reinterpret_cast<const float4*>(A + (size_t)d * kN + half * NH);
      float4 v0 = A4[0], v1 = A4[1];
      Ar[0]=v0.x*LOG2E; Ar[1]=v0.y*LOG2E; Ar[2]=v0.z*LOG2E; Ar[3]=v0.w*LOG2E;
      Ar[4]=v1.x*LOG2E; Ar[5]=v1.y*LOG2E; Ar[6]=v1.z*LOG2E; Ar[7]=v1.w*LOG2E;
    }
    const float4* B4 = reinterpret_cast<const float4*>(Bm + ((size_t)b * kN + half * NH) * kL);
    const float4* C4 = reinterpret_cast<const float4*>(Cm + ((size_t)b * kN + half * NH) * kL);

    // ---- Pass A: local scan from zero -> chunk aggregates (prod a, h_end)
    float cA[NH], cX[NH];
    #pragma unroll
    for (int n = 0; n < NH; ++n) {
      float4 b0 = B4[n*(kL/4) + tid];
      float Bv[T] = {b0.x, b0.y, b0.z, b0.w};
      float ap = 1.0f, h = 0.0f;
      #pragma unroll
      for (int i = 0; i < T; ++i) {
        float a = fast_exp2(sp[i] * Ar[n]);
        h  = a * h + du[i] * Bv[i];
        ap *= a;
      }
      cA[n] = ap; cX[n] = h;
    }

    // ---- Wave-level inclusive scan (Hillis-Steele, branchless identity select)
    #pragma unroll
    for (int n = 0; n < NH; ++n) {
      float a = cA[n], x = cX[n];
      #pragma unroll
      for (int off = 1; off < 64; off <<= 1) {
        float au = __shfl_up(a, (unsigned)off, 64);
        float xu = __shfl_up(x, (unsigned)off, 64);
        bool m = (lane >= off);
        au = m ? au : 1.0f;
        xu = m ? xu : 0.0f;
        x = a * xu + x;
        a = a * au;
      }
      cA[n] = a; cX[n] = x;
    }

    // ---- Cross-wave scan (8 waves) through LDS
    if (lane == 63) {
      #pragma unroll
      for (int n = 0; n < NH; ++n) { sA[wid][n] = cA[n]; sX[wid][n] = cX[n]; }
    }
    __syncthreads();
    if (tid < NH) {
      const int n = tid;
      float x = 0.0f;
      #pragma unroll
      for (int w = 0; w < NW; ++w) {
        eX[w][n] = x;                    // exclusive x-prefix for wave w
        x = sA[w][n] * x + sX[w][n];
      }
    }
    __syncthreads();

    // ---- Per-thread initial state, then Pass B fused with y accumulation
    #pragma unroll
    for (int n = 0; n < NH; ++n) {
      float al = __shfl_up(cA[n], 1u, 64);
      float xl = __shfl_up(cX[n], 1u, 64);
      if (lane == 0) { al = 1.0f; xl = 0.0f; }
      float h = al * eX[wid][n] + xl;    // h_{start-1}

      float4 b0 = B4[n*(kL/4) + tid];
      float4 c0 = C4[n*(kL/4) + tid];
      float Bv[T] = {b0.x, b0.y, b0.z, b0.w};
      float Cv[T] = {c0.x, c0.y, c0.z, c0.w};
      #pragma unroll
      for (int i = 0; i < T; ++i) {
        float a = fast_exp2(sp[i] * Ar[n]);
        h = a * h + du[i] * Bv[i];
        y[i] += Cv[i] * h;
      }
    }
    __syncthreads();   // protect sA/sX/eX reuse across halves
  }

  // ---- Epilogue: + u*D, * silu(z), store  (u refetched)
  const float Dd = Dv[d];
  const float4* z4 = reinterpret_cast<const float4*>(zm + roff);
  float4 z0 = z4[tid];
  float zv[T] = {z0.x, z0.y, z0.z, z0.w};
  float4 a0 = u4[tid];
  float uu[T] = {a0.x, a0.y, a0.z, a0.w};
  float ov[T];
  #pragma unroll
  for (int i = 0; i < T; ++i) {
    float yy  = y[i] + uu[i] * Dd;
    float sig = 1.0f / (1.0f + fast_exp(-zv[i]));
    ov[i] = yy * zv[i] * sig;
  }
  reinterpret_cast<float4*>(out + roff)[tid] = make_float4(ov[0], ov[1], ov[2], ov[3]);
}

extern "C" void kernel_launch(void* const* d_in, const int* in_sizes, int n_in,
                              void* d_out, int out_size, void* d_ws, size_t ws_size,
                              hipStream_t stream)
{
  const float* u  = (const float*)d_in[0];
  const float* dl = (const float*)d_in[1];
  const float* A  = (const float*)d_in[2];
  const float* Bm = (const float*)d_in[3];
  const float* Cm = (const float*)d_in[4];
  const float* Dv = (const float*)d_in[5];
  const float* zm = (const float*)d_in[6];
  float* out = (float*)d_out;
  const int rows = in_sizes[0] / kL;   // b*d = 2048
  selscan_kernel<<<rows, BLOCK, 0, stream>>>(u, dl, A, Bm, Cm, Dv, zm, out);
}

// Round 5
// 157.633 us; speedup vs baseline: 1.6951x; 1.0905x over previous
//
#include <hip/hip_runtime.h>
#include <cstdint>

// Shapes fixed by the harness:
// u, delta, z: (b=2, d=1024, l=2048) fp32; A: (d, n=16); B, C: (b, n, l); D: (d,)
constexpr int kD = 1024;
constexpr int kN = 16;
constexpr int kL = 2048;
constexpr int BLOCK = 512;
constexpr int T  = kL / BLOCK;   // 4 timesteps per thread (one float4)
constexpr int NW = BLOCK / 64;   // 8 waves per block
constexpr int NH = 8;            // states per half (kN/2)
constexpr float LOG2E = 1.44269504088896340736f;

__device__ __forceinline__ float fast_exp2(float x) { return __builtin_amdgcn_exp2f(x); }
__device__ __forceinline__ float fast_exp(float x)  { return __builtin_amdgcn_exp2f(x * LOG2E); }
__device__ __forceinline__ float softplus_f(float x) {
  return (x > 20.0f) ? x : __logf(1.0f + fast_exp(x));
}

// Single-arg launch_bounds ONLY: any min-waves hint triggers a spill cascade
// (R2: 48 VGPR + 350 MB scratch; R3: 64 VGPR + 260 MB). Structure > decree.
__global__ __launch_bounds__(BLOCK)
void selscan_kernel(const float* __restrict__ u,  const float* __restrict__ dl,
                    const float* __restrict__ A,  const float* __restrict__ Bm,
                    const float* __restrict__ Cm, const float* __restrict__ Dv,
                    const float* __restrict__ zm, float* __restrict__ out)
{
  const int row  = blockIdx.x;          // b*kD + d
  const int b    = row >> 10;           // kD = 1024
  const int d    = row & (kD - 1);
  const int tid  = threadIdx.x;
  const int lane = tid & 63;
  const int wid  = tid >> 6;

  const size_t roff = (size_t)row * kL;
  const float4* u4 = reinterpret_cast<const float4*>(u  + roff);
  const float4* d4 = reinterpret_cast<const float4*>(dl + roff);

  // Per-thread chunk [tid*T, tid*T+T): softplus(delta), delta*u in regs.
  float sp[T], du[T];
  {
    float4 a0 = u4[tid];
    float uu[T] = {a0.x, a0.y, a0.z, a0.w};
    float4 b0 = d4[tid];
    float dv[T] = {b0.x, b0.y, b0.z, b0.w};
    #pragma unroll
    for (int i = 0; i < T; ++i) { sp[i] = softplus_f(dv[i]); du[i] = sp[i] * uu[i]; }
  }

  float y[T];
  #pragma unroll
  for (int i = 0; i < T; ++i) y[i] = 0.0f;

  __shared__ float sA[NW][NH], sX[NW][NH], eX[NW][NH];

  #pragma unroll 1                      // halves sequential: live-range control
  for (int half = 0; half < 2; ++half) {
    // A sub-row, pre-scaled by log2(e): recurrence uses a single v_exp_f32
    float Ar[NH];
    {
      const float4* A4 = reinterpret_cast<const float4*>(A + (size_t)d * kN + half * NH);
      float4 v0 = A4[0], v1 = A4[1];
      Ar[0]=v0.x*LOG2E; Ar[1]=v0.y*LOG2E; Ar[2]=v0.z*LOG2E; Ar[3]=v0.w*LOG2E;
      Ar[4]=v1.x*LOG2E; Ar[5]=v1.y*LOG2E; Ar[6]=v1.z*LOG2E; Ar[7]=v1.w*LOG2E;
    }
    const float4* B4 = reinterpret_cast<const float4*>(Bm + ((size_t)b * kN + half * NH) * kL);
    const float4* C4 = reinterpret_cast<const float4*>(Cm + ((size_t)b * kN + half * NH) * kL);

    // ---- Pass A: local scan from zero. KEEP per-step local state hl and
    // prefix-product pp live (linearity: h_i = pp_i*h0 + hl_i) so the
    // post-scan pass needs NO B reload, NO exp recompute, NO serial chain.
    float hl[NH][T], pp[NH][T];
    #pragma unroll
    for (int n = 0; n < NH; ++n) {
      float4 b0 = B4[n*(kL/4) + tid];
      float Bv[T] = {b0.x, b0.y, b0.z, b0.w};
      float h = 0.0f, p = 1.0f;
      #pragma unroll
      for (int i = 0; i < T; ++i) {
        float a = fast_exp2(sp[i] * Ar[n]);
        h = a * h + du[i] * Bv[i];
        p *= a;
        hl[n][i] = h; pp[n][i] = p;
      }
    }

    // ---- Issue C loads NOW: independent of the scan, so the ~600-cycle
    // shuffle scan below hides their L2 latency.
    float4 cv[NH];
    #pragma unroll
    for (int n = 0; n < NH; ++n) cv[n] = C4[n*(kL/4) + tid];

    // ---- Wave-level inclusive scan on chunk aggregates (Hillis-Steele)
    float cA[NH], cX[NH];
    #pragma unroll
    for (int n = 0; n < NH; ++n) { cA[n] = pp[n][T-1]; cX[n] = hl[n][T-1]; }
    #pragma unroll
    for (int n = 0; n < NH; ++n) {
      float a = cA[n], x = cX[n];
      #pragma unroll
      for (int off = 1; off < 64; off <<= 1) {
        float au = __shfl_up(a, (unsigned)off, 64);
        float xu = __shfl_up(x, (unsigned)off, 64);
        bool m = (lane >= off);
        au = m ? au : 1.0f;
        xu = m ? xu : 0.0f;
        x = a * xu + x;
        a = a * au;
      }
      cA[n] = a; cX[n] = x;
    }

    // ---- Cross-wave scan (8 waves) through LDS
    if (lane == 63) {
      #pragma unroll
      for (int n = 0; n < NH; ++n) { sA[wid][n] = cA[n]; sX[wid][n] = cX[n]; }
    }
    __syncthreads();
    if (tid < NH) {
      const int n = tid;
      float x = 0.0f;
      #pragma unroll
      for (int w = 0; w < NW; ++w) {
        eX[w][n] = x;                    // exclusive x-prefix for wave w
        x = sA[w][n] * x + sX[w][n];
      }
    }
    __syncthreads();

    // ---- Apply: h_i = pp_i*h0 + hl_i;  y_i += C_i*h_i   (pure FMA, no loads)
    #pragma unroll
    for (int n = 0; n < NH; ++n) {
      float al = __shfl_up(cA[n], 1u, 64);
      float xl = __shfl_up(cX[n], 1u, 64);
      if (lane == 0) { al = 1.0f; xl = 0.0f; }
      float h0 = al * eX[wid][n] + xl;   // state entering this thread's chunk

      float Cv[T] = {cv[n].x, cv[n].y, cv[n].z, cv[n].w};
      #pragma unroll
      for (int i = 0; i < T; ++i) {
        float h = pp[n][i] * h0 + hl[n][i];
        y[i] += Cv[i] * h;
      }
    }
    __syncthreads();   // protect sA/sX/eX reuse across halves
  }

  // ---- Epilogue: + u*D, * silu(z), store  (u refetched; L2-hot)
  const float Dd = Dv[d];
  const float4* z4 = reinterpret_cast<const float4*>(zm + roff);
  float4 z0 = z4[tid];
  float zv[T] = {z0.x, z0.y, z0.z, z0.w};
  float4 a0 = u4[tid];
  float uu[T] = {a0.x, a0.y, a0.z, a0.w};
  float ov[T];
  #pragma unroll
  for (int i = 0; i < T; ++i) {
    float yy  = y[i] + uu[i] * Dd;
    float sig = 1.0f / (1.0f + fast_exp(-zv[i]));
    ov[i] = yy * zv[i] * sig;
  }
  reinterpret_cast<float4*>(out + roff)[tid] = make_float4(ov[0], ov[1], ov[2], ov[3]);
}

extern "C" void kernel_launch(void* const* d_in, const int* in_sizes, int n_in,
                              void* d_out, int out_size, void* d_ws, size_t ws_size,
                              hipStream_t stream)
{
  const float* u  = (const float*)d_in[0];
  const float* dl = (const float*)d_in[1];
  const float* A  = (const float*)d_in[2];
  const float* Bm = (const float*)d_in[3];
  const float* Cm = (const float*)d_in[4];
  const float* Dv = (const float*)d_in[5];
  const float* zm = (const float*)d_in[6];
  float* out = (float*)d_out;
  const int rows = in_sizes[0] / kL;   // b*d = 2048
  selscan_kernel<<<rows, BLOCK, 0, stream>>>(u, dl, A, Bm, Cm, Dv, zm, out);
}